// Round 1
// baseline (719.540 us; speedup 1.0000x reference)
//
#include <hip/hip_runtime.h>
#include <math.h>

#define NEG 0.1f
#define EPSV 1e-8f

constexpr int D  = 1024;
constexpr int TN = 256;   // output cols per block
constexpr int KC = 32;    // k chunk

// out[b][e] = scale * sum_{r valid} leaky( dot(A[b][r][:], W[e][:]) + bias[e] )
// A: [B][ROWS][D], W: [Dout=1024][D] row-major, valid r: r < min(ROWS, lens[b])
template<int ROWS, int RPT>
__global__ __launch_bounds__(256)
void vsum_kernel(const float* __restrict__ A,
                 const float* __restrict__ W,
                 const float* __restrict__ bias,
                 const int*   __restrict__ lens,
                 float scale,
                 float* __restrict__ out)
{
    constexpr int RSLOT = 16 * RPT;
    __shared__ float A_lds[RSLOT][KC + 4];
    __shared__ float Bt[KC][TN + 4];

    const int tid = threadIdx.x;
    const int tx  = tid & 15;   // col group (16 cols each)
    const int ty  = tid >> 4;   // row group (RPT rows each)
    const int b   = blockIdx.y;
    const int e0  = blockIdx.x * TN;

    float acc[RPT][16];
    #pragma unroll
    for (int r = 0; r < RPT; ++r)
        #pragma unroll
        for (int j = 0; j < 16; ++j) acc[r][j] = 0.f;

    const float* Ab = A + (size_t)b * ROWS * D;

    for (int k0 = 0; k0 < D; k0 += KC) {
        // stage A chunk [ROWS][KC]
        for (int idx = tid; idx < ROWS * (KC / 4); idx += 256) {
            int row = idx >> 3;          // KC/4 == 8
            int k4  = (idx & 7) << 2;
            float4 v = *(const float4*)(Ab + (size_t)row * D + k0 + k4);
            *(float4*)&A_lds[row][k4] = v;
        }
        // stage B chunk transposed: Bt[kk][e]
        for (int idx = tid; idx < TN * (KC / 4); idx += 256) {
            int e  = idx >> 3;
            int k4 = (idx & 7) << 2;
            float4 v = *(const float4*)(W + (size_t)(e0 + e) * D + k0 + k4);
            Bt[k4 + 0][e] = v.x;
            Bt[k4 + 1][e] = v.y;
            Bt[k4 + 2][e] = v.z;
            Bt[k4 + 3][e] = v.w;
        }
        __syncthreads();

        #pragma unroll 4
        for (int kk = 0; kk < KC; ++kk) {
            float a[RPT];
            #pragma unroll
            for (int r = 0; r < RPT; ++r) a[r] = A_lds[ty * RPT + r][kk];
            float4 b0 = *(const float4*)&Bt[kk][tx * 16 +  0];
            float4 b1 = *(const float4*)&Bt[kk][tx * 16 +  4];
            float4 b2 = *(const float4*)&Bt[kk][tx * 16 +  8];
            float4 b3 = *(const float4*)&Bt[kk][tx * 16 + 12];
            #pragma unroll
            for (int r = 0; r < RPT; ++r) {
                acc[r][ 0] += a[r] * b0.x; acc[r][ 1] += a[r] * b0.y;
                acc[r][ 2] += a[r] * b0.z; acc[r][ 3] += a[r] * b0.w;
                acc[r][ 4] += a[r] * b1.x; acc[r][ 5] += a[r] * b1.y;
                acc[r][ 6] += a[r] * b1.z; acc[r][ 7] += a[r] * b1.w;
                acc[r][ 8] += a[r] * b2.x; acc[r][ 9] += a[r] * b2.y;
                acc[r][10] += a[r] * b2.z; acc[r][11] += a[r] * b2.w;
                acc[r][12] += a[r] * b3.x; acc[r][13] += a[r] * b3.y;
                acc[r][14] += a[r] * b3.z; acc[r][15] += a[r] * b3.w;
            }
        }
        __syncthreads();
    }

    // epilogue: bias + leaky + mask, then reduce over rows
    const int lb = lens ? lens[b] : ROWS;
    float bv[16];
    #pragma unroll
    for (int j = 0; j < 16; ++j) bv[j] = bias[e0 + tx * 16 + j];

    float partial[16];
    #pragma unroll
    for (int j = 0; j < 16; ++j) partial[j] = 0.f;

    #pragma unroll
    for (int r = 0; r < RPT; ++r) {
        int row = ty * RPT + r;
        if (row < ROWS && row < lb) {
            #pragma unroll
            for (int j = 0; j < 16; ++j) {
                float v = acc[r][j] + bv[j];
                v = v > 0.f ? v : NEG * v;   // leaky BEFORE mask (matches ref)
                partial[j] += v;
            }
        }
    }

    float (*red)[TN + 4] = (float(*)[TN + 4])Bt;   // reuse Bt (KC >= 16 rows)
    #pragma unroll
    for (int j = 0; j < 16; ++j) red[ty][tx * 16 + j] = partial[j];
    __syncthreads();
    {
        const int col = tid;   // 256 threads -> 256 cols
        float s = 0.f;
        #pragma unroll
        for (int g = 0; g < 16; ++g) s += red[g][col];
        out[(size_t)b * D + e0 + col] = scale * s;
    }
}

// cap_vec[c] = l2norm( sum_{t<len} cap[c,t,:] / len )
__global__ __launch_bounds__(256)
void capvec_kernel(const float* __restrict__ cap, const int* __restrict__ lens,
                   float* __restrict__ capv)
{
    const int c = blockIdx.x, tid = threadIdx.x;
    const int len = lens[c];
    const float* base = cap + (size_t)c * 64 * D + tid * 4;
    float4 acc = make_float4(0.f, 0.f, 0.f, 0.f);
    for (int t = 0; t < len; ++t) {
        float4 v = *(const float4*)(base + (size_t)t * D);
        acc.x += v.x; acc.y += v.y; acc.z += v.z; acc.w += v.w;
    }
    const float inv = 1.f / (float)len;
    acc.x *= inv; acc.y *= inv; acc.z *= inv; acc.w *= inv;
    float ss = acc.x * acc.x + acc.y * acc.y + acc.z * acc.z + acc.w * acc.w;
    #pragma unroll
    for (int o = 32; o > 0; o >>= 1) ss += __shfl_xor(ss, o, 64);
    __shared__ float wsum[4];
    if ((tid & 63) == 0) wsum[tid >> 6] = ss;
    __syncthreads();
    const float total = wsum[0] + wsum[1] + wsum[2] + wsum[3];
    const float r = 1.f / (sqrtf(total) + EPSV);
    float4 o4 = make_float4(acc.x * r, acc.y * r, acc.z * r, acc.w * r);
    *(float4*)(capv + (size_t)c * D + tid * 4) = o4;
}

// sims[i,c] = (g*<ctx_c,cap_c> + <vb_i,cap_c>) /
//             (sqrt(g^2*|ctx_c|^2 + 2g*<ctx_c,vb_i> + |vb_i|^2) + eps)
__global__ __launch_bounds__(256)
void sims_kernel(const float* __restrict__ ctxbar, const float* __restrict__ vbar,
                 const float* __restrict__ capv, const float* __restrict__ gptr,
                 float* __restrict__ out)
{
    constexpr int KC3 = 256;
    __shared__ float Cx[16][KC3 + 4];
    __shared__ float Vb[16][KC3 + 4];
    __shared__ float Cp[16][KC3 + 4];
    const int tid = threadIdx.x;
    const int tx = tid & 15;   // c
    const int ty = tid >> 4;   // i
    const int c0 = blockIdx.x * 16, i0 = blockIdx.y * 16;

    float s1 = 0.f, s2 = 0.f, s3 = 0.f, s4 = 0.f, s5 = 0.f;
    for (int k0 = 0; k0 < D; k0 += KC3) {
        for (int idx = tid; idx < 16 * (KC3 / 4); idx += 256) {
            int row = idx >> 6;            // KC3/4 == 64
            int k4  = (idx & 63) << 2;
            *(float4*)&Cx[row][k4] = *(const float4*)(ctxbar + (size_t)(c0 + row) * D + k0 + k4);
            *(float4*)&Vb[row][k4] = *(const float4*)(vbar   + (size_t)(i0 + row) * D + k0 + k4);
            *(float4*)&Cp[row][k4] = *(const float4*)(capv   + (size_t)(c0 + row) * D + k0 + k4);
        }
        __syncthreads();
        #pragma unroll 8
        for (int k4 = 0; k4 < KC3 / 4; ++k4) {
            float4 xc = *(const float4*)&Cx[tx][k4 * 4];
            float4 xv = *(const float4*)&Vb[ty][k4 * 4];
            float4 xp = *(const float4*)&Cp[tx][k4 * 4];
            s1 += xc.x * xv.x + xc.y * xv.y + xc.z * xv.z + xc.w * xv.w;
            s2 += xv.x * xp.x + xv.y * xp.y + xv.z * xp.z + xv.w * xp.w;
            s3 += xc.x * xp.x + xc.y * xp.y + xc.z * xp.z + xc.w * xp.w;
            s4 += xc.x * xc.x + xc.y * xc.y + xc.z * xc.z + xc.w * xc.w;
            s5 += xv.x * xv.x + xv.y * xv.y + xv.z * xv.z + xv.w * xv.w;
        }
        __syncthreads();
    }
    const float g = *gptr;
    const float num = g * s3 + s2;
    const float den = sqrtf(g * g * s4 + 2.f * g * s1 + s5) + EPSV;
    out[(size_t)(i0 + ty) * 128 + (c0 + tx)] = num / den;
}

extern "C" void kernel_launch(void* const* d_in, const int* in_sizes, int n_in,
                              void* d_out, int out_size, void* d_ws, size_t ws_size,
                              hipStream_t stream)
{
    const float* img  = (const float*)d_in[0];   // [128,36,1024]
    const float* cap  = (const float*)d_in[1];   // [128,64,1024]
    const int*   lens = (const int*)  d_in[2];   // [128]
    const float* Wvi  = (const float*)d_in[7];   // [1024,1024]
    const float* bvi  = (const float*)d_in[8];
    const float* Wvt  = (const float*)d_in[9];   // [1024,1024]
    const float* bvt  = (const float*)d_in[10];
    const float* gamma = (const float*)d_in[11];
    // Wq/bq/Wk/bk/alpha/beta are dead: softmax-then-mean over the same axis == 1/R.

    float* out = (float*)d_out;
    float* ws  = (float*)d_ws;
    float* ctxbar = ws;                  // [128,1024]
    float* vbar   = ws + 128 * 1024;     // [128,1024]
    float* capv   = ws + 2 * 128 * 1024; // [128,1024]

    const float scale = 1.f / 36.f;      // attn_mean == 1/R exactly
    dim3 blk(256);
    vsum_kernel<64, 4><<<dim3(4, 128), blk, 0, stream>>>(cap, Wvt, bvt, lens, scale, ctxbar);
    vsum_kernel<36, 3><<<dim3(4, 128), blk, 0, stream>>>(img, Wvi, bvi, nullptr, scale, vbar);
    capvec_kernel<<<dim3(128), blk, 0, stream>>>(cap, lens, capv);
    sims_kernel<<<dim3(8, 8), blk, 0, stream>>>(ctxbar, vbar, capv, gamma, out);
}

// Round 2
// 241.129 us; speedup vs baseline: 2.9840x; 2.9840x over previous
//
#include <hip/hip_runtime.h>
#include <math.h>

#define NEG 0.1f
#define EPSV 1e-8f

constexpr int D = 1024;

typedef __bf16 bf16x8 __attribute__((ext_vector_type(8)));
typedef float  f32x4  __attribute__((ext_vector_type(4)));

__device__ inline bf16x8 cvt8(float4 a, float4 b) {
    bf16x8 r;
    r[0] = (__bf16)a.x; r[1] = (__bf16)a.y; r[2] = (__bf16)a.z; r[3] = (__bf16)a.w;
    r[4] = (__bf16)b.x; r[5] = (__bf16)b.y; r[6] = (__bf16)b.z; r[7] = (__bf16)b.w;
    return r;
}

// out[b][e] = scale * sum_{r < min(ROWS,lens[b])} leaky( dot(A[b][r][:], W[e][:]) + bias[e] )
// A: [B][ROWS][D] f32, W: [1024][D] f32 (B^T layout). MFMA bf16 16x16x32.
// LDS layout: row-major [rows][64 bf16], 16B slot index XOR-swizzled with (row&7).
template<int BM, int ROWS, int M_REP>
__global__ __launch_bounds__(256)
void vsum_mfma(const float* __restrict__ A,
               const float* __restrict__ W,
               const float* __restrict__ bias,
               const int*   __restrict__ lens,
               float scale,
               float* __restrict__ out)
{
    constexpr int BN = 128;
    constexpr int BK = 64;          // 8 slots of 8 bf16 per row
    constexpr int NK = D / BK;      // 16
    constexpr int N_REP = 2;        // per-wave: 32 cols = 2 n-frags

    __shared__ __bf16 Asm[BM * BK];
    __shared__ __bf16 Bsm[BN * BK];

    const int tid  = threadIdx.x;
    const int b    = blockIdx.y;
    const int e0   = blockIdx.x * BN;
    const int wid  = tid >> 6;
    const int lane = tid & 63;
    const int r16  = lane & 15;
    const int kg   = lane >> 4;     // 0..3

    const float* Ab = A + (size_t)b * ROWS * D;

    // ---- staging task assignment ----
    // A: BM rows x 4 ksegs (16 f32 each)
    const int  arow   = tid % BM;
    const int  akseg  = tid / BM;
    const bool a_act  = tid < BM * 4;
    const bool a_live = a_act && (arow < ROWS);
    const float* aptr = Ab + (size_t)arow * D + akseg * 16;
    // B: 128 rows x 2 khalves (32 f32 each)
    const int  brow = tid & 127;
    const int  bkh  = tid >> 7;
    const float* bptr = W + (size_t)(e0 + brow) * D + bkh * 32;

    float4 ra0, ra1, ra2, ra3;
    float4 rb0, rb1, rb2, rb3, rb4, rb5, rb6, rb7;

    f32x4 acc[M_REP][N_REP];
    #pragma unroll
    for (int mi = 0; mi < M_REP; ++mi)
        #pragma unroll
        for (int ni = 0; ni < N_REP; ++ni)
            acc[mi][ni] = (f32x4){0.f, 0.f, 0.f, 0.f};

    auto loadA = [&](int ks) {
        if (a_live) {
            const float* p = aptr + ks * BK;
            ra0 = *(const float4*)(p + 0);
            ra1 = *(const float4*)(p + 4);
            ra2 = *(const float4*)(p + 8);
            ra3 = *(const float4*)(p + 12);
        }
    };
    auto loadB = [&](int ks) {
        const float* p = bptr + ks * BK;
        rb0 = *(const float4*)(p + 0);  rb1 = *(const float4*)(p + 4);
        rb2 = *(const float4*)(p + 8);  rb3 = *(const float4*)(p + 12);
        rb4 = *(const float4*)(p + 16); rb5 = *(const float4*)(p + 20);
        rb6 = *(const float4*)(p + 24); rb7 = *(const float4*)(p + 28);
    };
    auto stage = [&]() {
        if (a_act) {
            bf16x8 w0, w1;
            if (a_live) { w0 = cvt8(ra0, ra1); w1 = cvt8(ra2, ra3); }
            else {
                #pragma unroll
                for (int j = 0; j < 8; ++j) { w0[j] = (__bf16)0.f; w1[j] = (__bf16)0.f; }
            }
            const int base = arow * BK, sw = arow & 7;
            *(bf16x8*)&Asm[base + (((akseg * 2 + 0) ^ sw) << 3)] = w0;
            *(bf16x8*)&Asm[base + (((akseg * 2 + 1) ^ sw) << 3)] = w1;
        }
        {
            bf16x8 w0 = cvt8(rb0, rb1), w1 = cvt8(rb2, rb3);
            bf16x8 w2 = cvt8(rb4, rb5), w3 = cvt8(rb6, rb7);
            const int base = brow * BK, sw = brow & 7, s0 = bkh * 4;
            *(bf16x8*)&Bsm[base + (((s0 + 0) ^ sw) << 3)] = w0;
            *(bf16x8*)&Bsm[base + (((s0 + 1) ^ sw) << 3)] = w1;
            *(bf16x8*)&Bsm[base + (((s0 + 2) ^ sw) << 3)] = w2;
            *(bf16x8*)&Bsm[base + (((s0 + 3) ^ sw) << 3)] = w3;
        }
    };
    auto compute = [&]() {
        #pragma unroll
        for (int ksub = 0; ksub < 2; ++ksub) {
            bf16x8 af[M_REP], bfr[N_REP];
            #pragma unroll
            for (int mi = 0; mi < M_REP; ++mi) {
                const int row = mi * 16 + r16;
                af[mi] = *(bf16x8*)&Asm[row * BK + (((ksub * 4 + kg) ^ (row & 7)) << 3)];
            }
            #pragma unroll
            for (int ni = 0; ni < N_REP; ++ni) {
                const int row = wid * 32 + ni * 16 + r16;
                bfr[ni] = *(bf16x8*)&Bsm[row * BK + (((ksub * 4 + kg) ^ (row & 7)) << 3)];
            }
            #pragma unroll
            for (int mi = 0; mi < M_REP; ++mi)
                #pragma unroll
                for (int ni = 0; ni < N_REP; ++ni)
                    acc[mi][ni] = __builtin_amdgcn_mfma_f32_16x16x32_bf16(
                        af[mi], bfr[ni], acc[mi][ni], 0, 0, 0);
        }
    };

    loadA(0); loadB(0);
    for (int ks = 0; ks < NK; ++ks) {
        stage();
        __syncthreads();
        if (ks + 1 < NK) { loadA(ks + 1); loadB(ks + 1); }  // prefetch hides under MFMA
        compute();
        __syncthreads();
    }

    // ---- fused epilogue: bias + leaky + row-mask + reduce over rows ----
    int lb = ROWS;
    if (lens) { const int lv = lens[b]; lb = lv < ROWS ? lv : ROWS; }

    float bv[N_REP], part[N_REP];
    #pragma unroll
    for (int ni = 0; ni < N_REP; ++ni) {
        bv[ni] = bias[e0 + wid * 32 + ni * 16 + r16];
        part[ni] = 0.f;
    }
    #pragma unroll
    for (int mi = 0; mi < M_REP; ++mi) {
        #pragma unroll
        for (int j = 0; j < 4; ++j) {
            const int row = mi * 16 + kg * 4 + j;
            if (row < lb) {
                #pragma unroll
                for (int ni = 0; ni < N_REP; ++ni) {
                    float v = acc[mi][ni][j] + bv[ni];
                    v = v > 0.f ? v : NEG * v;   // leaky before mask (ref order)
                    part[ni] += v;
                }
            }
        }
    }
    #pragma unroll
    for (int ni = 0; ni < N_REP; ++ni) {
        part[ni] += __shfl_xor(part[ni], 16, 64);
        part[ni] += __shfl_xor(part[ni], 32, 64);
    }
    if (kg < N_REP) {
        const float v = (kg == 0) ? part[0] : part[1];
        const int c = e0 + wid * 32 + kg * 16 + r16;
        out[(size_t)b * D + c] = scale * v;
    }
}

// cap_vec[c] = l2norm( sum_{t<len} cap[c,t,:] / len )
__global__ __launch_bounds__(256)
void capvec_kernel(const float* __restrict__ cap, const int* __restrict__ lens,
                   float* __restrict__ capv)
{
    const int c = blockIdx.x, tid = threadIdx.x;
    const int len = lens[c];
    const float* base = cap + (size_t)c * 64 * D + tid * 4;
    float4 acc = make_float4(0.f, 0.f, 0.f, 0.f);
    for (int t = 0; t < len; ++t) {
        float4 v = *(const float4*)(base + (size_t)t * D);
        acc.x += v.x; acc.y += v.y; acc.z += v.z; acc.w += v.w;
    }
    const float inv = 1.f / (float)len;
    acc.x *= inv; acc.y *= inv; acc.z *= inv; acc.w *= inv;
    float ss = acc.x * acc.x + acc.y * acc.y + acc.z * acc.z + acc.w * acc.w;
    #pragma unroll
    for (int o = 32; o > 0; o >>= 1) ss += __shfl_xor(ss, o, 64);
    __shared__ float wsum[4];
    if ((tid & 63) == 0) wsum[tid >> 6] = ss;
    __syncthreads();
    const float total = wsum[0] + wsum[1] + wsum[2] + wsum[3];
    const float r = 1.f / (sqrtf(total) + EPSV);
    float4 o4 = make_float4(acc.x * r, acc.y * r, acc.z * r, acc.w * r);
    *(float4*)(capv + (size_t)c * D + tid * 4) = o4;
}

// sims[i,c] = (g*<ctx_c,cap_c> + <vb_i,cap_c>) /
//             (sqrt(g^2*|ctx_c|^2 + 2g*<ctx_c,vb_i> + |vb_i|^2) + eps)
__global__ __launch_bounds__(256)
void sims_kernel(const float* __restrict__ ctxbar, const float* __restrict__ vbar,
                 const float* __restrict__ capv, const float* __restrict__ gptr,
                 float* __restrict__ out)
{
    constexpr int KC3 = 256;
    __shared__ float Cx[16][KC3 + 4];
    __shared__ float Vb[16][KC3 + 4];
    __shared__ float Cp[16][KC3 + 4];
    const int tid = threadIdx.x;
    const int tx = tid & 15;   // c
    const int ty = tid >> 4;   // i
    const int c0 = blockIdx.x * 16, i0 = blockIdx.y * 16;

    float s1 = 0.f, s2 = 0.f, s3 = 0.f, s4 = 0.f, s5 = 0.f;
    for (int k0 = 0; k0 < D; k0 += KC3) {
        for (int idx = tid; idx < 16 * (KC3 / 4); idx += 256) {
            int row = idx >> 6;
            int k4  = (idx & 63) << 2;
            *(float4*)&Cx[row][k4] = *(const float4*)(ctxbar + (size_t)(c0 + row) * D + k0 + k4);
            *(float4*)&Vb[row][k4] = *(const float4*)(vbar   + (size_t)(i0 + row) * D + k0 + k4);
            *(float4*)&Cp[row][k4] = *(const float4*)(capv   + (size_t)(c0 + row) * D + k0 + k4);
        }
        __syncthreads();
        #pragma unroll 8
        for (int k4 = 0; k4 < KC3 / 4; ++k4) {
            float4 xc = *(const float4*)&Cx[tx][k4 * 4];
            float4 xv = *(const float4*)&Vb[ty][k4 * 4];
            float4 xp = *(const float4*)&Cp[tx][k4 * 4];
            s1 += xc.x * xv.x + xc.y * xv.y + xc.z * xv.z + xc.w * xv.w;
            s2 += xv.x * xp.x + xv.y * xp.y + xv.z * xp.z + xv.w * xp.w;
            s3 += xc.x * xp.x + xc.y * xp.y + xc.z * xp.z + xc.w * xp.w;
            s4 += xc.x * xc.x + xc.y * xc.y + xc.z * xc.z + xc.w * xc.w;
            s5 += xv.x * xv.x + xv.y * xv.y + xv.z * xv.z + xv.w * xv.w;
        }
        __syncthreads();
    }
    const float g = *gptr;
    const float num = g * s3 + s2;
    const float den = sqrtf(g * g * s4 + 2.f * g * s1 + s5) + EPSV;
    out[(size_t)(i0 + ty) * 128 + (c0 + tx)] = num / den;
}

extern "C" void kernel_launch(void* const* d_in, const int* in_sizes, int n_in,
                              void* d_out, int out_size, void* d_ws, size_t ws_size,
                              hipStream_t stream)
{
    const float* img  = (const float*)d_in[0];   // [128,36,1024]
    const float* cap  = (const float*)d_in[1];   // [128,64,1024]
    const int*   lens = (const int*)  d_in[2];   // [128]
    const float* Wvi  = (const float*)d_in[7];   // [1024,1024]
    const float* bvi  = (const float*)d_in[8];
    const float* Wvt  = (const float*)d_in[9];   // [1024,1024]
    const float* bvt  = (const float*)d_in[10];
    const float* gamma = (const float*)d_in[11];
    // Wq/bq/Wk/bk/alpha/beta dead: softmax then mean over same axis == 1/R.

    float* out = (float*)d_out;
    float* ws  = (float*)d_ws;
    float* ctxbar = ws;                  // [128,1024]
    float* vbar   = ws + 128 * 1024;     // [128,1024]
    float* capv   = ws + 2 * 128 * 1024; // [128,1024]

    const float scale = 1.f / 36.f;      // attn_mean == 1/R exactly
    dim3 blk(256);
    vsum_mfma<64, 64, 4><<<dim3(8, 128), blk, 0, stream>>>(cap, Wvt, bvt, lens, scale, ctxbar);
    vsum_mfma<48, 36, 3><<<dim3(8, 128), blk, 0, stream>>>(img, Wvi, bvi, nullptr, scale, vbar);
    capvec_kernel<<<dim3(128), blk, 0, stream>>>(cap, lens, capv);
    sims_kernel<<<dim3(8, 8), blk, 0, stream>>>(ctxbar, vbar, capv, gamma, out);
}

// Round 3
// 125.740 us; speedup vs baseline: 5.7224x; 1.9177x over previous
//
#include <hip/hip_runtime.h>
#include <hip/hip_bf16.h>
#include <math.h>

#define NEG 0.1f
#define EPSV 1e-8f

constexpr int D  = 1024;
constexpr int BK = 64;        // k per step (8 slots of 8 bf16)
constexpr int NK = D / BK;    // 16
constexpr int BN = 128;

typedef __bf16 bf16x8 __attribute__((ext_vector_type(8)));
typedef float  f32x4  __attribute__((ext_vector_type(4)));

__device__ __forceinline__ bf16x8 cvt8(float4 a, float4 b) {
    bf16x8 r;
    r[0] = (__bf16)a.x; r[1] = (__bf16)a.y; r[2] = (__bf16)a.z; r[3] = (__bf16)a.w;
    r[4] = (__bf16)b.x; r[5] = (__bf16)b.y; r[6] = (__bf16)b.z; r[7] = (__bf16)b.w;
    return r;
}

// async global->LDS, 16B per lane; LDS dest is wave-uniform base + lane*16
__device__ __forceinline__ void gld_lds16(const __bf16* g, __bf16* l) {
    __builtin_amdgcn_global_load_lds(
        (__attribute__((address_space(1))) void*)(size_t)(const void*)g,
        (__attribute__((address_space(3))) void*)l,
        16, 0, 0);
}

// W f32 [1024][1024] -> bf16 pre-swizzled: Wsw[e][c*8 + s] = W[e][c*8 + (s^(e&7))]
// (16B slot granularity, swizzle within each 64-elem chunk)
__global__ __launch_bounds__(256)
void convert_w(const float* __restrict__ W0, const float* __restrict__ W1,
               __bf16* __restrict__ O0, __bf16* __restrict__ O1)
{
    int g = blockIdx.x * 256 + threadIdx.x;       // 2 * 1024 * 128 slot-tasks
    const float* src = (g < 131072) ? W0 : W1;
    __bf16*      dst = (g < 131072) ? O0 : O1;
    g &= 131071;
    const int e  = g >> 7;
    const int sl = g & 127;
    const int c  = sl >> 3, si = sl & 7;
    const int ss = (c << 3) | (si ^ (e & 7));
    const float* p = src + (size_t)e * D + ss * 8;
    float4 a = *(const float4*)p;
    float4 b = *(const float4*)(p + 4);
    *(bf16x8*)(dst + (size_t)e * D + sl * 8) = cvt8(a, b);
}

// out[b][e] = scale * sum_{t<lens[b]} leaky( dot(A[b][t][:], W[e][:]) + bias[e] )
// One block: 2 batch-groups (BM rows), BN=128 cols. A reg-staged f32->bf16,
// B via global_load_lds from pre-swizzled bf16 W. LDS double-buffered,
// ONE barrier per k-step.
template<int BM, int ROWS>
__global__ __launch_bounds__(256)
void vsum_mfma(const float* __restrict__ A,
               const __bf16* __restrict__ Wsw,
               const float* __restrict__ bias,
               const int*   __restrict__ lens,
               float scale,
               float* __restrict__ out)
{
    constexpr int G      = 2;
    constexpr int M_REP  = BM / 16;
    constexpr int N_REP  = 2;
    constexpr int ATASK  = BM * 4;     // 16-f32 segments per k-step

    __shared__ __bf16 Asm[2][BM * BK];
    __shared__ __bf16 Bsm[2][BN * BK];

    const int tid  = threadIdx.x;
    const int wid  = tid >> 6;
    const int lane = tid & 63;
    const int r16  = lane & 15;
    const int kg   = lane >> 4;
    const int e0   = blockIdx.x * BN;
    const int b0   = blockIdx.y * G;

    const float* Ab = A + (size_t)b0 * ROWS * D;

    // ---- A staging task assignment (2 tasks per thread max) ----
    int arow[2], aseg[2]; bool alive[2];
    const float* aptr[2];
    #pragma unroll
    for (int p = 0; p < 2; ++p) {
        const int task = tid + p * 256;
        const bool act = task < ATASK;
        const int r  = act ? (task % BM) : 0;
        const int ks = act ? (task / BM) : 0;
        arow[p] = r; aseg[p] = ks;
        alive[p] = act && (r < G * ROWS);
        aptr[p] = Ab + (size_t)r * D + ks * 16;
    }

    float4 ra[2][4];
    f32x4 acc[M_REP][N_REP];
    #pragma unroll
    for (int mi = 0; mi < M_REP; ++mi)
        #pragma unroll
        for (int ni = 0; ni < N_REP; ++ni)
            acc[mi][ni] = (f32x4){0.f, 0.f, 0.f, 0.f};

    auto loadA = [&](int ks) {
        #pragma unroll
        for (int p = 0; p < 2; ++p)
            if (alive[p]) {
                const float* q = aptr[p] + ks * BK;
                ra[p][0] = *(const float4*)(q + 0);
                ra[p][1] = *(const float4*)(q + 4);
                ra[p][2] = *(const float4*)(q + 8);
                ra[p][3] = *(const float4*)(q + 12);
            }
    };
    auto stageA = [&](int buf) {
        #pragma unroll
        for (int p = 0; p < 2; ++p)
            if (alive[p]) {
                bf16x8 w0 = cvt8(ra[p][0], ra[p][1]);
                bf16x8 w1 = cvt8(ra[p][2], ra[p][3]);
                const int base = arow[p] * BK, sw = arow[p] & 7;
                *(bf16x8*)&Asm[buf][base + (((aseg[p] * 2 + 0) ^ sw) << 3)] = w0;
                *(bf16x8*)&Asm[buf][base + (((aseg[p] * 2 + 1) ^ sw) << 3)] = w1;
            }
    };
    auto issueB = [&](int ks, int buf) {
        #pragma unroll
        for (int c = 0; c < 4; ++c) {
            const int rbase = (wid * 4 + c) * 8;          // 8 rows per call
            const int r = rbase + (lane >> 3);
            const __bf16* g = Wsw + (size_t)(e0 + r) * D + ks * BK + (lane & 7) * 8;
            gld_lds16(g, &Bsm[buf][rbase * BK]);          // uniform LDS base
        }
    };
    auto compute = [&](int buf) {
        #pragma unroll
        for (int ksub = 0; ksub < 2; ++ksub) {
            bf16x8 af[M_REP], bfr[N_REP];
            #pragma unroll
            for (int mi = 0; mi < M_REP; ++mi) {
                const int row = mi * 16 + r16;
                af[mi] = *(bf16x8*)&Asm[buf][row * BK + (((ksub * 4 + kg) ^ (row & 7)) << 3)];
            }
            #pragma unroll
            for (int ni = 0; ni < N_REP; ++ni) {
                const int row = wid * 32 + ni * 16 + r16;
                bfr[ni] = *(bf16x8*)&Bsm[buf][row * BK + (((ksub * 4 + kg) ^ (row & 7)) << 3)];
            }
            #pragma unroll
            for (int mi = 0; mi < M_REP; ++mi)
                #pragma unroll
                for (int ni = 0; ni < N_REP; ++ni)
                    acc[mi][ni] = __builtin_amdgcn_mfma_f32_16x16x32_bf16(
                        af[mi], bfr[ni], acc[mi][ni], 0, 0, 0);
        }
    };

    // prologue: stage k=0 into buf 0
    issueB(0, 0);
    loadA(0);
    stageA(0);
    __syncthreads();          // drains gload_lds (vmcnt) + ds_write (lgkm)

    int cur = 0;
    #pragma unroll 2
    for (int ks = 0; ks < NK; ++ks) {
        const bool more = (ks + 1) < NK;
        if (more) { issueB(ks + 1, cur ^ 1); loadA(ks + 1); }  // in flight across step
        compute(cur);
        if (more) stageA(cur ^ 1);
        __syncthreads();
        cur ^= 1;
    }

    // ---- epilogue: bias + leaky + per-group mask + reduce over rows ----
    int lb0 = ROWS, lb1 = ROWS;
    if (lens) {
        const int l0 = lens[b0], l1 = lens[b0 + 1];
        lb0 = l0 < ROWS ? l0 : ROWS;
        lb1 = l1 < ROWS ? l1 : ROWS;
    }

    float bv[N_REP];
    #pragma unroll
    for (int ni = 0; ni < N_REP; ++ni) bv[ni] = bias[e0 + wid * 32 + ni * 16 + r16];

    float part[2][N_REP];
    part[0][0] = part[0][1] = part[1][0] = part[1][1] = 0.f;

    #pragma unroll
    for (int mi = 0; mi < M_REP; ++mi) {
        #pragma unroll
        for (int j = 0; j < 4; ++j) {
            const int row = mi * 16 + kg * 4 + j;
            if (row < 2 * ROWS) {
                const int g  = row >= ROWS;
                const int t  = row - (g ? ROWS : 0);
                const int lb = g ? lb1 : lb0;
                if (t < lb) {
                    #pragma unroll
                    for (int ni = 0; ni < N_REP; ++ni) {
                        float v = acc[mi][ni][j] + bv[ni];
                        v = v > 0.f ? v : NEG * v;      // leaky before mask (ref order)
                        if (g) part[1][ni] += v; else part[0][ni] += v;
                    }
                }
            }
        }
    }
    #pragma unroll
    for (int g = 0; g < 2; ++g)
        #pragma unroll
        for (int ni = 0; ni < N_REP; ++ni) {
            part[g][ni] += __shfl_xor(part[g][ni], 16, 64);
            part[g][ni] += __shfl_xor(part[g][ni], 32, 64);
        }

    const float v = (kg == 0) ? part[0][0] : (kg == 1) ? part[0][1]
                  : (kg == 2) ? part[1][0] : part[1][1];
    const int gg = kg >> 1, nn = kg & 1;
    out[(size_t)(b0 + gg) * D + e0 + wid * 32 + nn * 16 + r16] = scale * v;
}

// cap_vec[c] = l2norm( sum_{t<len} cap[c,t,:] / len )
__global__ __launch_bounds__(256)
void capvec_kernel(const float* __restrict__ cap, const int* __restrict__ lens,
                   float* __restrict__ capv)
{
    const int c = blockIdx.x, tid = threadIdx.x;
    const int len = lens[c];
    const float* base = cap + (size_t)c * 64 * D + tid * 4;
    float4 acc = make_float4(0.f, 0.f, 0.f, 0.f);
    for (int t = 0; t < len; ++t) {
        float4 v = *(const float4*)(base + (size_t)t * D);
        acc.x += v.x; acc.y += v.y; acc.z += v.z; acc.w += v.w;
    }
    const float inv = 1.f / (float)len;
    acc.x *= inv; acc.y *= inv; acc.z *= inv; acc.w *= inv;
    float ss = acc.x * acc.x + acc.y * acc.y + acc.z * acc.z + acc.w * acc.w;
    #pragma unroll
    for (int o = 32; o > 0; o >>= 1) ss += __shfl_xor(ss, o, 64);
    __shared__ float wsum[4];
    if ((tid & 63) == 0) wsum[tid >> 6] = ss;
    __syncthreads();
    const float total = wsum[0] + wsum[1] + wsum[2] + wsum[3];
    const float r = 1.f / (sqrtf(total) + EPSV);
    float4 o4 = make_float4(acc.x * r, acc.y * r, acc.z * r, acc.w * r);
    *(float4*)(capv + (size_t)c * D + tid * 4) = o4;
}

// sims[i,c] = (g*<ctx_c,cap_c> + <vb_i,cap_c>) /
//             (sqrt(g^2*|ctx_c|^2 + 2g*<ctx_c,vb_i> + |vb_i|^2) + eps)
__global__ __launch_bounds__(256)
void sims_kernel(const float* __restrict__ ctxbar, const float* __restrict__ vbar,
                 const float* __restrict__ capv, const float* __restrict__ gptr,
                 float* __restrict__ out)
{
    constexpr int KC3 = 256;
    __shared__ float Cx[16][KC3 + 4];
    __shared__ float Vb[16][KC3 + 4];
    __shared__ float Cp[16][KC3 + 4];
    const int tid = threadIdx.x;
    const int tx = tid & 15;   // c
    const int ty = tid >> 4;   // i
    const int c0 = blockIdx.x * 16, i0 = blockIdx.y * 16;

    float s1 = 0.f, s2 = 0.f, s3 = 0.f, s4 = 0.f, s5 = 0.f;
    for (int k0 = 0; k0 < D; k0 += KC3) {
        for (int idx = tid; idx < 16 * (KC3 / 4); idx += 256) {
            int row = idx >> 6;
            int k4  = (idx & 63) << 2;
            *(float4*)&Cx[row][k4] = *(const float4*)(ctxbar + (size_t)(c0 + row) * D + k0 + k4);
            *(float4*)&Vb[row][k4] = *(const float4*)(vbar   + (size_t)(i0 + row) * D + k0 + k4);
            *(float4*)&Cp[row][k4] = *(const float4*)(capv   + (size_t)(c0 + row) * D + k0 + k4);
        }
        __syncthreads();
        #pragma unroll 8
        for (int k4 = 0; k4 < KC3 / 4; ++k4) {
            float4 xc = *(const float4*)&Cx[tx][k4 * 4];
            float4 xv = *(const float4*)&Vb[ty][k4 * 4];
            float4 xp = *(const float4*)&Cp[tx][k4 * 4];
            s1 += xc.x * xv.x + xc.y * xv.y + xc.z * xv.z + xc.w * xv.w;
            s2 += xv.x * xp.x + xv.y * xp.y + xv.z * xp.z + xv.w * xp.w;
            s3 += xc.x * xp.x + xc.y * xp.y + xc.z * xp.z + xc.w * xp.w;
            s4 += xc.x * xc.x + xc.y * xc.y + xc.z * xc.z + xc.w * xc.w;
            s5 += xv.x * xv.x + xv.y * xv.y + xv.z * xv.z + xv.w * xv.w;
        }
        __syncthreads();
    }
    const float g = *gptr;
    const float num = g * s3 + s2;
    const float den = sqrtf(g * g * s4 + 2.f * g * s1 + s5) + EPSV;
    out[(size_t)(i0 + ty) * 128 + (c0 + tx)] = num / den;
}

extern "C" void kernel_launch(void* const* d_in, const int* in_sizes, int n_in,
                              void* d_out, int out_size, void* d_ws, size_t ws_size,
                              hipStream_t stream)
{
    const float* img  = (const float*)d_in[0];   // [128,36,1024]
    const float* cap  = (const float*)d_in[1];   // [128,64,1024]
    const int*   lens = (const int*)  d_in[2];   // [128]
    const float* Wvi  = (const float*)d_in[7];   // [1024,1024]
    const float* bvi  = (const float*)d_in[8];
    const float* Wvt  = (const float*)d_in[9];   // [1024,1024]
    const float* bvt  = (const float*)d_in[10];
    const float* gamma = (const float*)d_in[11];
    // Wq/bq/Wk/bk/alpha/beta dead: softmax then mean over same axis == 1/R.

    float* out = (float*)d_out;

    // workspace layout: [0,2MB) Wvt bf16 swz | [2,4MB) Wvi bf16 swz |
    //                   then ctxbar/vbar/capv f32 (512KB each)
    __bf16* wtb = (__bf16*)d_ws;
    __bf16* wib = wtb + (size_t)1024 * 1024;
    float* ctxbar = (float*)(wib + (size_t)1024 * 1024);
    float* vbar   = ctxbar + 128 * 1024;
    float* capv   = vbar   + 128 * 1024;

    const float scale = 1.f / 36.f;      // attn_mean == 1/R exactly
    dim3 blk(256);
    convert_w<<<dim3(1024), blk, 0, stream>>>(Wvt, Wvi, wtb, wib);
    vsum_mfma<128, 64><<<dim3(8, 64), blk, 0, stream>>>(cap, wtb, bvt, lens, scale, ctxbar);
    vsum_mfma< 80, 36><<<dim3(8, 64), blk, 0, stream>>>(img, wib, bvi, nullptr, scale, vbar);
    capvec_kernel<<<dim3(128), blk, 0, stream>>>(cap, lens, capv);
    sims_kernel<<<dim3(8, 8), blk, 0, stream>>>(ctxbar, vbar, capv, gamma, out);
}

// Round 4
// 84.352 us; speedup vs baseline: 8.5302x; 1.4907x over previous
//
#include <hip/hip_runtime.h>
#include <hip/hip_bf16.h>
#include <math.h>

#define NEG 0.1f
#define EPSV 1e-8f

constexpr int D  = 1024;
constexpr int BK = 64;        // k per step (8 slots of 8 bf16)
constexpr int NK = D / BK;    // 16
constexpr int BN = 128;

typedef __bf16 bf16x8 __attribute__((ext_vector_type(8)));
typedef __bf16 bf16x4 __attribute__((ext_vector_type(4)));
typedef float  f32x4  __attribute__((ext_vector_type(4)));

__device__ __forceinline__ bf16x8 cvt8(float4 a, float4 b) {
    bf16x8 r;
    r[0] = (__bf16)a.x; r[1] = (__bf16)a.y; r[2] = (__bf16)a.z; r[3] = (__bf16)a.w;
    r[4] = (__bf16)b.x; r[5] = (__bf16)b.y; r[6] = (__bf16)b.z; r[7] = (__bf16)b.w;
    return r;
}

// async global->LDS, 16B per lane; LDS dest is wave-uniform base + lane*16
__device__ __forceinline__ void gld_lds16(const __bf16* g, __bf16* l) {
    __builtin_amdgcn_global_load_lds(
        (__attribute__((address_space(1))) void*)(size_t)(const void*)g,
        (__attribute__((address_space(3))) void*)l,
        16, 0, 0);
}

// W f32 [1024][1024] -> bf16 pre-swizzled: slot s holds orig slot s^(e&7)
__global__ __launch_bounds__(256)
void convert_w(const float* __restrict__ W0, const float* __restrict__ W1,
               __bf16* __restrict__ O0, __bf16* __restrict__ O1)
{
    int g = blockIdx.x * 256 + threadIdx.x;       // 2 * 1024 * 128 slot-tasks
    const float* src = (g < 131072) ? W0 : W1;
    __bf16*      dst = (g < 131072) ? O0 : O1;
    g &= 131071;
    const int e  = g >> 7;
    const int sl = g & 127;
    const int c  = sl >> 3, si = sl & 7;
    const int ss = (c << 3) | (si ^ (e & 7));
    const float* p = src + (size_t)e * D + ss * 8;
    float4 a = *(const float4*)p;
    float4 b = *(const float4*)(p + 4);
    *(bf16x8*)(dst + (size_t)e * D + sl * 8) = cvt8(a, b);
}

// img f32 [128*36][1024] -> bf16 [128*40][1024], rows padded to 40/batch (zeros),
// slot-swizzled with key = (t & 7)  (dst row Rd = c*40+t, Rd&7 == t&7 since 40%8==0)
__global__ __launch_bounds__(256)
void convert_img(const float* __restrict__ src, __bf16* __restrict__ dst)
{
    const int g  = blockIdx.x * 256 + threadIdx.x;   // 5120 * 128 tasks
    const int Rd = g >> 7, sl = g & 127;
    const int c  = Rd / 40, t = Rd - c * 40;
    bf16x8 w;
    if (t < 36) {
        const int ch = sl >> 3, u = sl & 7;
        const int s2 = (ch << 3) | (u ^ (t & 7));
        const float* p = src + (size_t)(c * 36 + t) * D + s2 * 8;
        w = cvt8(*(const float4*)p, *(const float4*)(p + 4));
    } else {
        #pragma unroll
        for (int j = 0; j < 8; ++j) w[j] = (__bf16)0.f;
    }
    *(bf16x8*)(dst + (size_t)Rd * D + sl * 8) = w;
}

// cap f32 [128*64][1024] -> bf16 swizzled (key = t&7) AND fused cap_vec:
// capv[c] = l2norm( sum_{t<len} cap[c,t,:] / len ). 512 threads, row-halved.
__global__ __launch_bounds__(512)
void convert_cap(const float* __restrict__ cap, const int* __restrict__ lens,
                 __bf16* __restrict__ dst, float* __restrict__ capv)
{
    __shared__ float part[4][512];
    __shared__ float wsum[4];
    const int c    = blockIdx.x;
    const int tid  = threadIdx.x;
    const int half = tid >> 8;
    const int ts   = tid & 255;
    const int col  = ts * 4;
    const int cb   = col & ~63;          // 64-elem chunk base
    const int u    = (col >> 3) & 7;     // slot within chunk
    const int lo   = col & 7;            // 0 or 4
    const int len  = lens[c];
    const float* src = cap + (size_t)c * 64 * D + col;
    __bf16* drow = dst + (size_t)c * 64 * D;

    float4 acc = make_float4(0.f, 0.f, 0.f, 0.f);
    #pragma unroll 4
    for (int tt = 0; tt < 32; ++tt) {
        const int t = half * 32 + tt;
        float4 v = *(const float4*)(src + (size_t)t * D);
        if (t < len) { acc.x += v.x; acc.y += v.y; acc.z += v.z; acc.w += v.w; }
        bf16x4 w;
        w[0] = (__bf16)v.x; w[1] = (__bf16)v.y; w[2] = (__bf16)v.z; w[3] = (__bf16)v.w;
        *(bf16x4*)(drow + (size_t)t * D + cb + ((u ^ (t & 7)) << 3) + lo) = w;
    }
    part[0][tid] = acc.x; part[1][tid] = acc.y;
    part[2][tid] = acc.z; part[3][tid] = acc.w;
    __syncthreads();
    if (tid < 256) {
        acc.x += part[0][tid + 256]; acc.y += part[1][tid + 256];
        acc.z += part[2][tid + 256]; acc.w += part[3][tid + 256];
        const float inv = 1.f / (float)len;
        acc.x *= inv; acc.y *= inv; acc.z *= inv; acc.w *= inv;
        float ss = acc.x * acc.x + acc.y * acc.y + acc.z * acc.z + acc.w * acc.w;
        #pragma unroll
        for (int o = 32; o > 0; o >>= 1) ss += __shfl_xor(ss, o, 64);
        if ((tid & 63) == 0) wsum[tid >> 6] = ss;
    }
    __syncthreads();
    if (tid < 256) {
        const float total = wsum[0] + wsum[1] + wsum[2] + wsum[3];
        const float r = 1.f / (sqrtf(total) + EPSV);
        float4 o4 = make_float4(acc.x * r, acc.y * r, acc.z * r, acc.w * r);
        *(float4*)(capv + (size_t)c * D + col) = o4;
    }
}

// ---------- primary GEMM: all-async staging, XCD batch-partition ----------
// out[b][e] = scale * sum_{t<lens[b]} leaky( dot(A[b][t][:], W[e][:]) + bias[e] )
// Acvt: bf16 pre-swizzled [B*RPAD][1024]; Wsw: bf16 pre-swizzled [1024][1024].
template<int RPAD, int ROWS>
__global__ __launch_bounds__(256)
void vsum_mfma_async(const __bf16* __restrict__ Acvt,
                     const __bf16* __restrict__ Wsw,
                     const float* __restrict__ bias,
                     const int*   __restrict__ lens,
                     float scale,
                     float* __restrict__ out)
{
    constexpr int G      = 2;
    constexpr int BM     = G * RPAD;        // 128 (cap) / 80 (img)
    constexpr int M_REP  = BM / 16;         // 8 / 5
    constexpr int N_REP  = 2;
    constexpr int ACALLS = (BM / 8 + 3) / 4;

    __shared__ __bf16 Asm[2][BM * BK];
    __shared__ __bf16 Bsm[2][BN * BK];

    const int tid  = threadIdx.x;
    const int wid  = tid >> 6;
    const int lane = tid & 63;
    const int r16  = lane & 15;
    const int kg   = lane >> 4;

    // XCD-aware: xcd = wg&7 (HW round-robin heuristic). Each XCD owns a
    // contiguous batch range (16 batches) x all 8 e-columns -> per-XCD
    // working set ~ 2.1 MB A + 2 MB W, L2-resident.
    const int wg  = blockIdx.x;             // 0..511
    const int xcd = wg & 7;
    const int idx = wg >> 3;                // 0..63
    const int jj  = idx & 7;                // e-column
    const int y   = xcd * 8 + (idx >> 3);   // batch-group 0..63
    const int e0  = jj * BN;
    const int b0  = y * G;

    const __bf16* Ab = Acvt + (size_t)b0 * RPAD * D;

    f32x4 acc[M_REP][N_REP];
    #pragma unroll
    for (int mi = 0; mi < M_REP; ++mi)
        #pragma unroll
        for (int ni = 0; ni < N_REP; ++ni)
            acc[mi][ni] = (f32x4){0.f, 0.f, 0.f, 0.f};

    auto issueA = [&](int ks, int buf) {
        #pragma unroll
        for (int cc = 0; cc < ACALLS; ++cc) {
            const int rbase = (wid + cc * 4) * 8;       // 8 rows / wave-call
            if (rbase < BM) {
                const int r = rbase + (lane >> 3);
                gld_lds16(Ab + (size_t)r * D + ks * BK + (lane & 7) * 8,
                          &Asm[buf][rbase * BK]);
            }
        }
    };
    auto issueB = [&](int ks, int buf) {
        #pragma unroll
        for (int cc = 0; cc < 4; ++cc) {
            const int rbase = (wid * 4 + cc) * 8;
            const int r = rbase + (lane >> 3);
            gld_lds16(Wsw + (size_t)(e0 + r) * D + ks * BK + (lane & 7) * 8,
                      &Bsm[buf][rbase * BK]);
        }
    };
    auto compute = [&](int buf) {
        #pragma unroll
        for (int ksub = 0; ksub < 2; ++ksub) {
            bf16x8 af[M_REP], bfr[N_REP];
            #pragma unroll
            for (int mi = 0; mi < M_REP; ++mi) {
                const int row = mi * 16 + r16;
                af[mi] = *(bf16x8*)&Asm[buf][row * BK + (((ksub * 4 + kg) ^ (row & 7)) << 3)];
            }
            #pragma unroll
            for (int ni = 0; ni < N_REP; ++ni) {
                const int row = wid * 32 + ni * 16 + r16;
                bfr[ni] = *(bf16x8*)&Bsm[buf][row * BK + (((ksub * 4 + kg) ^ (row & 7)) << 3)];
            }
            #pragma unroll
            for (int mi = 0; mi < M_REP; ++mi)
                #pragma unroll
                for (int ni = 0; ni < N_REP; ++ni)
                    acc[mi][ni] = __builtin_amdgcn_mfma_f32_16x16x32_bf16(
                        af[mi], bfr[ni], acc[mi][ni], 0, 0, 0);
        }
    };

    issueA(0, 0); issueB(0, 0);
    __syncthreads();                       // drains vmcnt for buf0
    int cur = 0;
    #pragma unroll 2
    for (int ks = 0; ks < NK; ++ks) {
        if (ks + 1 < NK) { issueA(ks + 1, cur ^ 1); issueB(ks + 1, cur ^ 1); }
        compute(cur);
        __syncthreads();                   // drains next-step loads + ds_reads
        cur ^= 1;
    }

    // ---- epilogue: bias + leaky + per-group mask + reduce over rows ----
    int lb0 = ROWS, lb1 = ROWS;
    if (lens) {
        const int l0 = lens[b0], l1 = lens[b0 + 1];
        lb0 = l0 < ROWS ? l0 : ROWS;
        lb1 = l1 < ROWS ? l1 : ROWS;
    }
    float bv[N_REP];
    #pragma unroll
    for (int ni = 0; ni < N_REP; ++ni) bv[ni] = bias[e0 + wid * 32 + ni * 16 + r16];

    float part[2][N_REP];
    part[0][0] = part[0][1] = part[1][0] = part[1][1] = 0.f;

    #pragma unroll
    for (int mi = 0; mi < M_REP; ++mi) {
        #pragma unroll
        for (int j = 0; j < 4; ++j) {
            const int row = mi * 16 + kg * 4 + j;
            const int g   = row >= RPAD;
            const int t   = row - (g ? RPAD : 0);
            const int lb  = g ? lb1 : lb0;
            if (t < lb) {
                #pragma unroll
                for (int ni = 0; ni < N_REP; ++ni) {
                    float v = acc[mi][ni][j] + bv[ni];
                    v = v > 0.f ? v : NEG * v;       // leaky before mask (ref order)
                    if (g) part[1][ni] += v; else part[0][ni] += v;
                }
            }
        }
    }
    #pragma unroll
    for (int g = 0; g < 2; ++g)
        #pragma unroll
        for (int ni = 0; ni < N_REP; ++ni) {
            part[g][ni] += __shfl_xor(part[g][ni], 16, 64);
            part[g][ni] += __shfl_xor(part[g][ni], 32, 64);
        }
    const float v = (kg == 0) ? part[0][0] : (kg == 1) ? part[0][1]
                  : (kg == 2) ? part[1][0] : part[1][1];
    const int gg = kg >> 1, nn = kg & 1;
    out[(size_t)(b0 + gg) * D + e0 + wid * 32 + nn * 16 + r16] = scale * v;
}

// ---------- fallback (proven R3 path, used if ws too small) ----------
template<int BM, int ROWS>
__global__ __launch_bounds__(256)
void vsum_mfma_rs(const float* __restrict__ A,
                  const __bf16* __restrict__ Wsw,
                  const float* __restrict__ bias,
                  const int*   __restrict__ lens,
                  float scale,
                  float* __restrict__ out)
{
    constexpr int G      = 2;
    constexpr int M_REP  = BM / 16;
    constexpr int N_REP  = 2;
    constexpr int ATASK  = BM * 4;

    __shared__ __bf16 Asm[2][BM * BK];
    __shared__ __bf16 Bsm[2][BN * BK];

    const int tid  = threadIdx.x;
    const int wid  = tid >> 6;
    const int lane = tid & 63;
    const int r16  = lane & 15;
    const int kg   = lane >> 4;
    const int e0   = blockIdx.x * BN;
    const int b0   = blockIdx.y * G;

    const float* Ab = A + (size_t)b0 * ROWS * D;

    int arow[2], aseg[2]; bool alive[2];
    const float* aptr[2];
    #pragma unroll
    for (int p = 0; p < 2; ++p) {
        const int task = tid + p * 256;
        const bool act = task < ATASK;
        const int r  = act ? (task % BM) : 0;
        const int ks = act ? (task / BM) : 0;
        arow[p] = r; aseg[p] = ks;
        alive[p] = act && (r < G * ROWS);
        aptr[p] = Ab + (size_t)r * D + ks * 16;
    }

    float4 ra[2][4];
    f32x4 acc[M_REP][N_REP];
    #pragma unroll
    for (int mi = 0; mi < M_REP; ++mi)
        #pragma unroll
        for (int ni = 0; ni < N_REP; ++ni)
            acc[mi][ni] = (f32x4){0.f, 0.f, 0.f, 0.f};

    auto loadA = [&](int ks) {
        #pragma unroll
        for (int p = 0; p < 2; ++p)
            if (alive[p]) {
                const float* q = aptr[p] + ks * BK;
                ra[p][0] = *(const float4*)(q + 0);
                ra[p][1] = *(const float4*)(q + 4);
                ra[p][2] = *(const float4*)(q + 8);
                ra[p][3] = *(const float4*)(q + 12);
            }
    };
    auto stageA = [&](int buf) {
        #pragma unroll
        for (int p = 0; p < 2; ++p)
            if (alive[p]) {
                bf16x8 w0 = cvt8(ra[p][0], ra[p][1]);
                bf16x8 w1 = cvt8(ra[p][2], ra[p][3]);
                const int base = arow[p] * BK, sw = arow[p] & 7;
                *(bf16x8*)&Asm[buf][base + (((aseg[p] * 2 + 0) ^ sw) << 3)] = w0;
                *(bf16x8*)&Asm[buf][base + (((aseg[p] * 2 + 1) ^ sw) << 3)] = w1;
            }
    };
    auto issueB = [&](int ks, int buf) {
        #pragma unroll
        for (int c = 0; c < 4; ++c) {
            const int rbase = (wid * 4 + c) * 8;
            const int r = rbase + (lane >> 3);
            const __bf16* g = Wsw + (size_t)(e0 + r) * D + ks * BK + (lane & 7) * 8;
            gld_lds16(g, &Bsm[buf][rbase * BK]);
        }
    };
    auto compute = [&](int buf) {
        #pragma unroll
        for (int ksub = 0; ksub < 2; ++ksub) {
            bf16x8 af[M_REP], bfr[N_REP];
            #pragma unroll
            for (int mi = 0; mi < M_REP; ++mi) {
                const int row = mi * 16 + r16;
                af[mi] = *(bf16x8*)&Asm[buf][row * BK + (((ksub * 4 + kg) ^ (row & 7)) << 3)];
            }
            #pragma unroll
            for (int ni = 0; ni < N_REP; ++ni) {
                const int row = wid * 32 + ni * 16 + r16;
                bfr[ni] = *(bf16x8*)&Bsm[buf][row * BK + (((ksub * 4 + kg) ^ (row & 7)) << 3)];
            }
            #pragma unroll
            for (int mi = 0; mi < M_REP; ++mi)
                #pragma unroll
                for (int ni = 0; ni < N_REP; ++ni)
                    acc[mi][ni] = __builtin_amdgcn_mfma_f32_16x16x32_bf16(
                        af[mi], bfr[ni], acc[mi][ni], 0, 0, 0);
        }
    };

    issueB(0, 0);
    loadA(0);
    stageA(0);
    __syncthreads();

    int cur = 0;
    #pragma unroll 2
    for (int ks = 0; ks < NK; ++ks) {
        const bool more = (ks + 1) < NK;
        if (more) { issueB(ks + 1, cur ^ 1); loadA(ks + 1); }
        compute(cur);
        if (more) stageA(cur ^ 1);
        __syncthreads();
        cur ^= 1;
    }

    int lb0 = ROWS, lb1 = ROWS;
    if (lens) {
        const int l0 = lens[b0], l1 = lens[b0 + 1];
        lb0 = l0 < ROWS ? l0 : ROWS;
        lb1 = l1 < ROWS ? l1 : ROWS;
    }
    float bv[N_REP];
    #pragma unroll
    for (int ni = 0; ni < N_REP; ++ni) bv[ni] = bias[e0 + wid * 32 + ni * 16 + r16];
    float part[2][N_REP];
    part[0][0] = part[0][1] = part[1][0] = part[1][1] = 0.f;
    #pragma unroll
    for (int mi = 0; mi < M_REP; ++mi) {
        #pragma unroll
        for (int j = 0; j < 4; ++j) {
            const int row = mi * 16 + kg * 4 + j;
            if (row < 2 * ROWS) {
                const int g  = row >= ROWS;
                const int t  = row - (g ? ROWS : 0);
                const int lb = g ? lb1 : lb0;
                if (t < lb) {
                    #pragma unroll
                    for (int ni = 0; ni < N_REP; ++ni) {
                        float v = acc[mi][ni][j] + bv[ni];
                        v = v > 0.f ? v : NEG * v;
                        if (g) part[1][ni] += v; else part[0][ni] += v;
                    }
                }
            }
        }
    }
    #pragma unroll
    for (int g = 0; g < 2; ++g)
        #pragma unroll
        for (int ni = 0; ni < N_REP; ++ni) {
            part[g][ni] += __shfl_xor(part[g][ni], 16, 64);
            part[g][ni] += __shfl_xor(part[g][ni], 32, 64);
        }
    const float v = (kg == 0) ? part[0][0] : (kg == 1) ? part[0][1]
                  : (kg == 2) ? part[1][0] : part[1][1];
    const int gg = kg >> 1, nn = kg & 1;
    out[(size_t)(b0 + gg) * D + e0 + wid * 32 + nn * 16 + r16] = scale * v;
}

__global__ __launch_bounds__(256)
void capvec_kernel(const float* __restrict__ cap, const int* __restrict__ lens,
                   float* __restrict__ capv)
{
    const int c = blockIdx.x, tid = threadIdx.x;
    const int len = lens[c];
    const float* base = cap + (size_t)c * 64 * D + tid * 4;
    float4 acc = make_float4(0.f, 0.f, 0.f, 0.f);
    for (int t = 0; t < len; ++t) {
        float4 v = *(const float4*)(base + (size_t)t * D);
        acc.x += v.x; acc.y += v.y; acc.z += v.z; acc.w += v.w;
    }
    const float inv = 1.f / (float)len;
    acc.x *= inv; acc.y *= inv; acc.z *= inv; acc.w *= inv;
    float ss = acc.x * acc.x + acc.y * acc.y + acc.z * acc.z + acc.w * acc.w;
    #pragma unroll
    for (int o = 32; o > 0; o >>= 1) ss += __shfl_xor(ss, o, 64);
    __shared__ float wsum[4];
    if ((tid & 63) == 0) wsum[tid >> 6] = ss;
    __syncthreads();
    const float total = wsum[0] + wsum[1] + wsum[2] + wsum[3];
    const float r = 1.f / (sqrtf(total) + EPSV);
    float4 o4 = make_float4(acc.x * r, acc.y * r, acc.z * r, acc.w * r);
    *(float4*)(capv + (size_t)c * D + tid * 4) = o4;
}

// sims[i,c] = (g*<ctx_c,cap_c> + <vb_i,cap_c>) /
//             (sqrt(g^2*|ctx_c|^2 + 2g*<ctx_c,vb_i> + |vb_i|^2) + eps)
__global__ __launch_bounds__(256)
void sims_kernel(const float* __restrict__ ctxbar, const float* __restrict__ vbar,
                 const float* __restrict__ capv, const float* __restrict__ gptr,
                 float* __restrict__ out)
{
    constexpr int KC3 = 256;
    __shared__ float Cx[16][KC3 + 4];
    __shared__ float Vb[16][KC3 + 4];
    __shared__ float Cp[16][KC3 + 4];
    const int tid = threadIdx.x;
    const int tx = tid & 15;
    const int ty = tid >> 4;
    const int c0 = blockIdx.x * 16, i0 = blockIdx.y * 16;

    float s1 = 0.f, s2 = 0.f, s3 = 0.f, s4 = 0.f, s5 = 0.f;
    for (int k0 = 0; k0 < D; k0 += KC3) {
        for (int idx = tid; idx < 16 * (KC3 / 4); idx += 256) {
            int row = idx >> 6;
            int k4  = (idx & 63) << 2;
            *(float4*)&Cx[row][k4] = *(const float4*)(ctxbar + (size_t)(c0 + row) * D + k0 + k4);
            *(float4*)&Vb[row][k4] = *(const float4*)(vbar   + (size_t)(i0 + row) * D + k0 + k4);
            *(float4*)&Cp[row][k4] = *(const float4*)(capv   + (size_t)(c0 + row) * D + k0 + k4);
        }
        __syncthreads();
        #pragma unroll 8
        for (int k4 = 0; k4 < KC3 / 4; ++k4) {
            float4 xc = *(const float4*)&Cx[tx][k4 * 4];
            float4 xv = *(const float4*)&Vb[ty][k4 * 4];
            float4 xp = *(const float4*)&Cp[tx][k4 * 4];
            s1 += xc.x * xv.x + xc.y * xv.y + xc.z * xv.z + xc.w * xv.w;
            s2 += xv.x * xp.x + xv.y * xp.y + xv.z * xp.z + xv.w * xp.w;
            s3 += xc.x * xp.x + xc.y * xp.y + xc.z * xp.z + xc.w * xp.w;
            s4 += xc.x * xc.x + xc.y * xc.y + xc.z * xc.z + xc.w * xc.w;
            s5 += xv.x * xv.x + xv.y * xv.y + xv.z * xv.z + xv.w * xv.w;
        }
        __syncthreads();
    }
    const float g = *gptr;
    const float num = g * s3 + s2;
    const float den = sqrtf(g * g * s4 + 2.f * g * s1 + s5) + EPSV;
    out[(size_t)(i0 + ty) * 128 + (c0 + tx)] = num / den;
}

extern "C" void kernel_launch(void* const* d_in, const int* in_sizes, int n_in,
                              void* d_out, int out_size, void* d_ws, size_t ws_size,
                              hipStream_t stream)
{
    const float* img  = (const float*)d_in[0];   // [128,36,1024]
    const float* cap  = (const float*)d_in[1];   // [128,64,1024]
    const int*   lens = (const int*)  d_in[2];   // [128]
    const float* Wvi  = (const float*)d_in[7];   // [1024,1024]
    const float* bvi  = (const float*)d_in[8];
    const float* Wvt  = (const float*)d_in[9];   // [1024,1024]
    const float* bvt  = (const float*)d_in[10];
    const float* gamma = (const float*)d_in[11];
    // Wq/bq/Wk/bk/alpha/beta dead: softmax then mean over same axis == 1/R.

    float* out = (float*)d_out;
    const float scale = 1.f / 36.f;      // attn_mean == 1/R exactly
    dim3 blk(256);

    // primary ws layout (bytes): wtb 2M | wib 2M | capb 16M | imgb 10M | 3x512K f32
    const size_t NEED = 4194304ull + 16777216ull + 10485760ull + 1572864ull;

    if (ws_size >= NEED) {
        __bf16* wtb  = (__bf16*)d_ws;
        __bf16* wib  = wtb + (size_t)1024 * 1024;
        __bf16* capb = wib + (size_t)1024 * 1024;            // 128*64*1024
        __bf16* imgb = capb + (size_t)128 * 64 * 1024;       // 128*40*1024
        float* ctxbar = (float*)(imgb + (size_t)128 * 40 * 1024);
        float* vbar   = ctxbar + 128 * 1024;
        float* capv   = vbar   + 128 * 1024;

        convert_w  <<<dim3(1024), blk, 0, stream>>>(Wvt, Wvi, wtb, wib);
        convert_img<<<dim3(2560), blk, 0, stream>>>(img, imgb);
        convert_cap<<<dim3(128), dim3(512), 0, stream>>>(cap, lens, capb, capv);
        vsum_mfma_async<64, 64><<<dim3(512), blk, 0, stream>>>(capb, wtb, bvt, lens, scale, ctxbar);
        vsum_mfma_async<40, 36><<<dim3(512), blk, 0, stream>>>(imgb, wib, bvi, nullptr, scale, vbar);
        sims_kernel<<<dim3(8, 8), blk, 0, stream>>>(ctxbar, vbar, capv, gamma, out);
    } else {
        // fallback: R3 path (needs 5.5 MB)
        __bf16* wtb = (__bf16*)d_ws;
        __bf16* wib = wtb + (size_t)1024 * 1024;
        float* ctxbar = (float*)(wib + (size_t)1024 * 1024);
        float* vbar   = ctxbar + 128 * 1024;
        float* capv   = vbar   + 128 * 1024;

        convert_w<<<dim3(1024), blk, 0, stream>>>(Wvt, Wvi, wtb, wib);
        vsum_mfma_rs<128, 64><<<dim3(8, 64), blk, 0, stream>>>(cap, wtb, bvt, lens, scale, ctxbar);
        vsum_mfma_rs< 80, 36><<<dim3(8, 64), blk, 0, stream>>>(img, wib, bvi, nullptr, scale, vbar);
        capvec_kernel<<<dim3(128), blk, 0, stream>>>(cap, lens, capv);
        sims_kernel<<<dim3(8, 8), blk, 0, stream>>>(ctxbar, vbar, capv, gamma, out);
    }
}